// Round 10
// baseline (163.870 us; speedup 1.0000x reference)
//
#include <hip/hip_runtime.h>

#define N_TOK 3136   // 56*56
#define WOUT 56
#define CH 512
#define HD 64

typedef _Float16 h4 __attribute__((ext_vector_type(4)));
typedef _Float16 h8 __attribute__((ext_vector_type(8)));
typedef float f32x4 __attribute__((ext_vector_type(4)));
typedef float f32x16 __attribute__((ext_vector_type(16)));
typedef unsigned u32x2 __attribute__((ext_vector_type(2)));
typedef unsigned u32x4 __attribute__((ext_vector_type(4)));

// ws offsets in f16 elements
#define WS_XH 0
#define WS_XL 3211264
#define WS_WF 6422528
#define WS_QT 7208960
#define WS_KT 10420224
#define WS_VW 13631488
#define WS_ML 16842752          // f32 m/l arrays start here (byte offset = 2*this)
#define SPLIT_O 3211264         // per-split partial-O element count (16*64*3136)
#define ML_N 100352             // 2*16*3136 per array

__device__ inline unsigned pkh(float a, float b) {
    return __builtin_bit_cast(unsigned, __builtin_amdgcn_cvt_pkrtz(a, b));
}
// swap: lanes>=32 of a  <->  lanes<32 of b
__device__ inline void plswap(unsigned& a, unsigned& b) {
#if __has_builtin(__builtin_amdgcn_permlane32_swap)
    u32x2 r = __builtin_amdgcn_permlane32_swap(a, b, false, false);
    a = r.x; b = r.y;
#else
    unsigned a2 = (unsigned)__shfl_xor((int)a, 32);
    unsigned b2 = (unsigned)__shfl_xor((int)b, 32);
    bool hi = (threadIdx.x & 63) >= 32;
    unsigned na = hi ? b2 : a;
    unsigned nb = hi ? b : a2;
    a = na; b = nb;
#endif
}

// ---------- downsample + transpose + f16 split ----------
__global__ __launch_bounds__(256) void k_ds(const float* __restrict__ x,
                                            _Float16* __restrict__ xh,
                                            _Float16* __restrict__ xl) {
    __shared__ float tile[64 * 65];
    const int t = threadIdx.x, q = t >> 6, l = t & 63;
    const int n0 = blockIdx.x * 64, c0 = blockIdx.y * 64, b = blockIdx.z;
    #pragma unroll
    for (int r = 0; r < 16; ++r) {
        int c_l = q * 16 + r;
        int n = n0 + l;
        int hh = n / WOUT, ww = n - hh * WOUT;
        tile[c_l * 65 + l] =
            x[(((size_t)(b * CH + c0 + c_l)) * 112 + hh * 2) * 112 + ww * 2];
    }
    __syncthreads();
    #pragma unroll
    for (int r = 0; r < 16; ++r) {
        int n_l = q * 16 + r;
        float v = tile[l * 65 + n_l];
        _Float16 hi = (_Float16)v;
        _Float16 lo = (_Float16)(v - (float)hi);
        size_t base = ((size_t)b * N_TOK + n0 + n_l) * CH + c0 + l;
        xh[base] = hi;
        xl[base] = lo;
    }
}

__global__ __launch_bounds__(256) void k_wcvt(const float* __restrict__ w, _Float16* __restrict__ wf) {
    int i = blockIdx.x * 256 + threadIdx.x;
    wf[i] = (_Float16)w[i];
}

// ---------- projection (unchanged) ----------
__global__ __launch_bounds__(256) void k_proj(const _Float16* __restrict__ wf,
                                              const _Float16* __restrict__ xh,
                                              const _Float16* __restrict__ xl,
                                              _Float16* __restrict__ qT,
                                              _Float16* __restrict__ kT,
                                              _Float16* __restrict__ vW) {
    __shared__ __align__(16) _Float16 Wt[64 * 40];
    __shared__ __align__(16) _Float16 Xh[64 * 40];
    __shared__ __align__(16) _Float16 Xl[64 * 40];
    const int t = threadIdx.x;
    const int n0 = blockIdx.x * 64, o0 = blockIdx.y * 64, b = blockIdx.z;
    const int w = t >> 6, L = t & 63, lm = L & 15, g = L >> 4;
    const int wo = w >> 1, wn = w & 1;
    const int sr = t >> 2, sc = (t & 3) * 8;

    f32x4 acc[2][2] = {};
    for (int kc = 0; kc < 16; ++kc) {
        const int c0 = kc * 32;
        __syncthreads();
        *(h8*)&Wt[sr * 40 + sc] = *(const h8*)&wf[(size_t)(o0 + sr) * CH + c0 + sc];
        *(h8*)&Xh[sr * 40 + sc] = *(const h8*)&xh[((size_t)b * N_TOK + n0 + sr) * CH + c0 + sc];
        *(h8*)&Xl[sr * 40 + sc] = *(const h8*)&xl[((size_t)b * N_TOK + n0 + sr) * CH + c0 + sc];
        __syncthreads();
        h8 a0 = *(h8*)&Wt[(wo * 32 + lm) * 40 + g * 8];
        h8 a1 = *(h8*)&Wt[(wo * 32 + 16 + lm) * 40 + g * 8];
        h8 b0h = *(h8*)&Xh[(wn * 32 + lm) * 40 + g * 8];
        h8 b1h = *(h8*)&Xh[(wn * 32 + 16 + lm) * 40 + g * 8];
        h8 b0l = *(h8*)&Xl[(wn * 32 + lm) * 40 + g * 8];
        h8 b1l = *(h8*)&Xl[(wn * 32 + 16 + lm) * 40 + g * 8];
        acc[0][0] = __builtin_amdgcn_mfma_f32_16x16x32_f16(a0, b0h, acc[0][0], 0, 0, 0);
        acc[0][0] = __builtin_amdgcn_mfma_f32_16x16x32_f16(a0, b0l, acc[0][0], 0, 0, 0);
        acc[0][1] = __builtin_amdgcn_mfma_f32_16x16x32_f16(a0, b1h, acc[0][1], 0, 0, 0);
        acc[0][1] = __builtin_amdgcn_mfma_f32_16x16x32_f16(a0, b1l, acc[0][1], 0, 0, 0);
        acc[1][0] = __builtin_amdgcn_mfma_f32_16x16x32_f16(a1, b0h, acc[1][0], 0, 0, 0);
        acc[1][0] = __builtin_amdgcn_mfma_f32_16x16x32_f16(a1, b0l, acc[1][0], 0, 0, 0);
        acc[1][1] = __builtin_amdgcn_mfma_f32_16x16x32_f16(a1, b1h, acc[1][1], 0, 0, 0);
        acc[1][1] = __builtin_amdgcn_mfma_f32_16x16x32_f16(a1, b1l, acc[1][1], 0, 0, 0);
    }
    #pragma unroll
    for (int ot = 0; ot < 2; ++ot) {
        int obase = o0 + wo * 32 + ot * 16;
        int h = obase / 192;
        int typ = (obase / 64) % 3;
        int dbase = (wo * 32 + ot * 16) & 63;
        #pragma unroll
        for (int nt = 0; nt < 2; ++nt) {
            int n = n0 + wn * 32 + nt * 16 + lm;
            f32x4 a = acc[ot][nt];
            if (typ == 2) {
                #pragma unroll
                for (int j = 0; j < 4; ++j)
                    vW[((size_t)(b * 8 + h) * HD + dbase + g * 4 + j) * N_TOK + n] = (_Float16)a[j];
            } else {
                h4 hv = {(_Float16)a[0], (_Float16)a[1], (_Float16)a[2], (_Float16)a[3]};
                _Float16* dst = (typ == 0) ? qT : kT;
                *(h4*)&dst[((size_t)(b * 8 + h) * N_TOK + n) * HD + dbase + g * 4] = hv;
            }
        }
    }
}

// ---------- flash attention, key-split S=2, single-buffer LDS, defer-max ----------
__global__ __launch_bounds__(128, 3) void k_attn5(const _Float16* __restrict__ qT,
                                                  const _Float16* __restrict__ kT,
                                                  const _Float16* __restrict__ vW,
                                                  _Float16* __restrict__ pO,
                                                  float* __restrict__ pm,
                                                  float* __restrict__ pl) {
    __shared__ __align__(16) _Float16 Ks[64 * 72];   // [n][d], pitch 72 halves
    __shared__ __align__(16) _Float16 Vs[64 * 72];   // [d][n], pitch 72

    const int t = threadIdx.x;
    const int w = t >> 6, L = t & 63, lm = L & 31, hi = L >> 5;

    // bijective chunked XCD swizzle: 1568 blocks = 8 XCDs x 196
    const int lin = blockIdx.x + 49 * blockIdx.y + 784 * blockIdx.z;
    const int nl = (lin & 7) * 196 + (lin >> 3);
    const int combo = nl / 49;              // 0..31 : (split, bh)
    const int mt = nl - combo * 49;
    const int bh = combo & 15;
    const int split = combo >> 4;
    const int mw = mt * 64 + w * 32;

    const int cs = split ? 25 : 0;          // chunk range [cs, ce)
    const int ce = split ? 49 : 25;

    // hoist Q (B-operand): lane: query col = lm, k-slice = hi*8
    const size_t qb = ((size_t)bh * N_TOK + mw + lm) * HD;
    h8 qf[4];
    #pragma unroll
    for (int ks = 0; ks < 4; ++ks) qf[ks] = *(const h8*)&qT[qb + ks * 16 + hi * 8];

    const int sr = t >> 1;                  // staging row 0..63
    const int scol = (t & 1) * 32;          // element offset within row
    const _Float16* ka = kT + (size_t)bh * N_TOK * HD + (size_t)(cs * 64 + sr) * HD + scol;
    const _Float16* va = vW + (size_t)bh * HD * N_TOK + (size_t)sr * N_TOK + cs * 64 + scol;

    float m_run = -1e30f, l_run = 0.f;
    f32x16 o_acc[2] = {};

    // prologue: stage first chunk
    {
        h8 pk[4], pv[4];
        #pragma unroll
        for (int i = 0; i < 4; ++i) { pk[i] = *(const h8*)&ka[i * 8]; pv[i] = *(const h8*)&va[i * 8]; }
        ka += 64 * HD; va += 64;
        #pragma unroll
        for (int i = 0; i < 4; ++i) {
            *(h8*)&Ks[sr * 72 + scol + i * 8] = pk[i];
            *(h8*)&Vs[sr * 72 + scol + i * 8] = pv[i];
        }
    }
    __syncthreads();

    for (int ch = cs; ch < ce; ++ch) {
        const bool pf = (ch + 1 < ce);
        h8 pk[4], pv[4];
        if (pf) {   // issue next-chunk loads early; latency hides under compute
            #pragma unroll
            for (int i = 0; i < 4; ++i) { pk[i] = *(const h8*)&ka[i * 8]; pv[i] = *(const h8*)&va[i * 8]; }
            ka += 64 * HD; va += 64;
        }

        // QK^T (swapped): A = K rows (keys), B = Q; D[key][query]
        f32x16 s0 = {}, s1 = {};
        __builtin_amdgcn_s_setprio(1);
        #pragma unroll
        for (int ks = 0; ks < 4; ++ks) {
            h8 a0 = *(const h8*)&Ks[lm * 72 + ks * 16 + hi * 8];
            h8 a1 = *(const h8*)&Ks[(32 + lm) * 72 + ks * 16 + hi * 8];
            s0 = __builtin_amdgcn_mfma_f32_32x32x16_f16(a0, qf[ks], s0, 0, 0, 0);
            s1 = __builtin_amdgcn_mfma_f32_32x32x16_f16(a1, qf[ks], s1, 0, 0, 0);
        }
        __builtin_amdgcn_s_setprio(0);

        // online softmax with defer-max (THR=5): lane owns query lm (paired with lane^32)
        float cmax = -1e30f;
        #pragma unroll
        for (int r = 0; r < 16; ++r) cmax = fmaxf(cmax, fmaxf(s0[r], s1[r]));
        cmax = fmaxf(cmax, __shfl_xor(cmax, 32));
        if (!__all(cmax - m_run <= 5.f)) {
            float mnew = fmaxf(m_run, cmax);
            float alpha = __expf(m_run - mnew);
            m_run = mnew;
            l_run *= alpha;
            #pragma unroll
            for (int r = 0; r < 16; ++r) { o_acc[0][r] *= alpha; o_acc[1][r] *= alpha; }
        }
        float p[2][16];
        float psum = 0.f;
        #pragma unroll
        for (int r = 0; r < 16; ++r) {
            p[0][r] = __expf(s0[r] - m_run);
            p[1][r] = __expf(s1[r] - m_run);
            psum += p[0][r] + p[1][r];
        }
        psum += __shfl_xor(psum, 32);
        l_run += psum;

        // P -> B-operand fragments in-register (cvt_pkrtz + permlane32_swap)
        h8 pfrag[4];
        #pragma unroll
        for (int kt = 0; kt < 2; ++kt) {
            #pragma unroll
            for (int half = 0; half < 2; ++half) {
                const int b0 = half * 8;
                unsigned w01 = pkh(p[kt][b0 + 0], p[kt][b0 + 1]);
                unsigned w23 = pkh(p[kt][b0 + 2], p[kt][b0 + 3]);
                unsigned w45 = pkh(p[kt][b0 + 4], p[kt][b0 + 5]);
                unsigned w67 = pkh(p[kt][b0 + 6], p[kt][b0 + 7]);
                plswap(w01, w45);
                plswap(w23, w67);
                u32x4 uu = {w01, w23, w45, w67};
                pfrag[kt * 2 + half] = __builtin_bit_cast(h8, uu);
            }
        }

        // PV: A = V rows (d), B = P; D[d][query]
        __builtin_amdgcn_s_setprio(1);
        #pragma unroll
        for (int ns = 0; ns < 4; ++ns) {
            h8 av0 = *(const h8*)&Vs[lm * 72 + ns * 16 + hi * 8];
            h8 av1 = *(const h8*)&Vs[(32 + lm) * 72 + ns * 16 + hi * 8];
            o_acc[0] = __builtin_amdgcn_mfma_f32_32x32x16_f16(av0, pfrag[ns], o_acc[0], 0, 0, 0);
            o_acc[1] = __builtin_amdgcn_mfma_f32_32x32x16_f16(av1, pfrag[ns], o_acc[1], 0, 0, 0);
        }
        __builtin_amdgcn_s_setprio(0);

        if (pf) {
            __syncthreads();   // all waves done reading Ks/Vs
            #pragma unroll
            for (int i = 0; i < 4; ++i) {
                *(h8*)&Ks[sr * 72 + scol + i * 8] = pk[i];
                *(h8*)&Vs[sr * 72 + scol + i * 8] = pv[i];
            }
            __syncthreads();   // new tile visible
        }
    }

    // epilogue: store unnormalized partial O (f16) + m,l (f32)
    const size_t pob = (size_t)split * SPLIT_O + (size_t)bh * HD * N_TOK + mw + lm;
    #pragma unroll
    for (int dt = 0; dt < 2; ++dt)
        #pragma unroll
        for (int r = 0; r < 16; ++r) {
            int d = dt * 32 + (r & 3) + 8 * (r >> 2) + 4 * hi;
            pO[pob + (size_t)d * N_TOK] = (_Float16)o_acc[dt][r];
        }
    if (hi == 0) {
        pm[(split * 16 + bh) * N_TOK + mw + lm] = m_run;
        pl[(split * 16 + bh) * N_TOK + mw + lm] = l_run;
    }
}

// ---------- combine the two key-splits ----------
__global__ __launch_bounds__(256) void k_comb(const _Float16* __restrict__ pO,
                                              const float* __restrict__ pm,
                                              const float* __restrict__ pl,
                                              float* __restrict__ out) {
    int idx = blockIdx.x * 256 + threadIdx.x;   // 16*64*3136 = 12544*256 exactly
    int n = idx % N_TOK;
    int bh = (idx / N_TOK) >> 6;
    float m1 = pm[bh * N_TOK + n],              l1 = pl[bh * N_TOK + n];
    float m2 = pm[16 * N_TOK + bh * N_TOK + n], l2 = pl[16 * N_TOK + bh * N_TOK + n];
    float mm = fmaxf(m1, m2);
    float w1 = __expf(m1 - mm), w2 = __expf(m2 - mm);
    float O1 = (float)pO[idx];
    float O2 = (float)pO[SPLIT_O + idx];
    out[idx] = (O1 * w1 + O2 * w2) / (l1 * w1 + l2 * w2);
}

extern "C" void kernel_launch(void* const* d_in, const int* in_sizes, int n_in,
                              void* d_out, int out_size, void* d_ws, size_t ws_size,
                              hipStream_t stream) {
    const float* x = (const float*)d_in[0];
    const float* wq = (const float*)d_in[1];
    float* out = (float*)d_out;
    _Float16* ws = (_Float16*)d_ws;

    _Float16* xh = ws + WS_XH;
    _Float16* xl = ws + WS_XL;
    _Float16* wf = ws + WS_WF;
    _Float16* qT = ws + WS_QT;
    _Float16* kT = ws + WS_KT;
    _Float16* vW = ws + WS_VW;
    _Float16* pO = ws;                       // overlays xh/xl (dead after k_proj)
    float* pm = (float*)(ws + WS_ML);
    float* pl = pm + ML_N;

    k_ds<<<dim3(49, 8, 2), 256, 0, stream>>>(x, xh, xl);
    k_wcvt<<<dim3(3072), 256, 0, stream>>>(wq, wf);
    k_proj<<<dim3(49, 24, 2), 256, 0, stream>>>(wf, xh, xl, qT, kT, vW);
    k_attn5<<<dim3(49, 16, 2), 128, 0, stream>>>(qT, kT, vW, pO, pm, pl);
    k_comb<<<dim3(12544), 256, 0, stream>>>(pO, pm, pl, out);
}